// Round 6
// baseline (483.175 us; speedup 1.0000x reference)
//
#include <hip/hip_runtime.h>
#include <hip/hip_bf16.h>

typedef unsigned short u16;
typedef unsigned int   u32;

static constexpr int Bc = 8, Ac = 64, Tc = 128, Cc = 256, Hc = 8;
static constexpr int NROW = Bc * Ac * Tc;   // 65536 tokens
static constexpr int DH = Cc / Hc;          // 32

__device__ __forceinline__ float bf2f(u16 h) {
    u32 u = ((u32)h) << 16; float f; __builtin_memcpy(&f, &u, 4); return f;
}
__device__ __forceinline__ u16 f2bf(float f) {
    u32 u; __builtin_memcpy(&u, &f, 4);
    u += 0x7fffu + ((u >> 16) & 1u);   // RNE
    return (u16)(u >> 16);
}

typedef __attribute__((ext_vector_type(8))) short  short8v;
typedef __attribute__((ext_vector_type(4))) float  float4v;

__device__ __forceinline__ void gload16(const void* g, const void* lds) {
    __builtin_amdgcn_global_load_lds(
        (const __attribute__((address_space(1))) void*)g,
        (__attribute__((address_space(3))) void*)lds, 16, 0, 0);
}

#define MFMA16(a, b, c) __builtin_amdgcn_mfma_f32_16x16x32_bf16((a), (b), (c), 0, 0, 0)

// ---------------- cast all weights fp32 -> bf16, one launch ----------------
__global__ void cast4_kernel(const float* __restrict__ a, int na,
                             const float* __restrict__ b, int nb,
                             const float* __restrict__ c, int nc,
                             const float* __restrict__ d, int nd,
                             u16* oa, u16* ob, u16* oc, u16* od) {
    int i = blockIdx.x * 256 + threadIdx.x;
    if (i < na) { oa[i] = f2bf(a[i]); return; }
    i -= na;
    if (i < nb) { ob[i] = f2bf(b[i]); return; }
    i -= nb;
    if (i < nc) { oc[i] = f2bf(c[i]); return; }
    i -= nc;
    if (i < nd) { od[i] = f2bf(d[i]); }
}

// ---------------- LayerNorm, fp32 input -> bf16 out ----------------
__global__ __launch_bounds__(256) void ln_f32(const float* __restrict__ in,
        const float* __restrict__ w, const float* __restrict__ b,
        u16* __restrict__ out) {
    int row  = blockIdx.x * 4 + (threadIdx.x >> 6);
    int lane = threadIdx.x & 63;
    const float* rp = in + (size_t)row * Cc + lane * 4;
    float4 v = *(const float4*)rp;
    float s  = v.x + v.y + v.z + v.w;
    float sq = v.x * v.x + v.y * v.y + v.z * v.z + v.w * v.w;
    for (int off = 32; off; off >>= 1) { s += __shfl_xor(s, off); sq += __shfl_xor(sq, off); }
    float mean = s * (1.f / Cc);
    float rs = rsqrtf(sq * (1.f / Cc) - mean * mean + 1e-5f);
    int c0 = lane * 4;
    float vv[4] = {v.x, v.y, v.z, v.w};
    ushort4 ov;
    ov.x = f2bf((vv[0] - mean) * rs * w[c0 + 0] + b[c0 + 0]);
    ov.y = f2bf((vv[1] - mean) * rs * w[c0 + 1] + b[c0 + 1]);
    ov.z = f2bf((vv[2] - mean) * rs * w[c0 + 2] + b[c0 + 2]);
    ov.w = f2bf((vv[3] - mean) * rs * w[c0 + 3] + b[c0 + 3]);
    *(ushort4*)(out + (size_t)row * Cc + c0) = ov;
}

// ---- GEMM, A-in-registers: out[64-rows/block][Nf] = X[.][256] @ W[Nf][256]^T ----
// 4 waves: wave=(mrow-half, ncol-half); NJ chunks of 64 cols; weight dbuf in LDS.
// EPI: 0 bias->bf16 | 1 bias+res->bf16
template<int NJ, int EPI>
__global__ __launch_bounds__(256) void gemm_breg(
        const u16* __restrict__ X, const u16* __restrict__ W,
        const float* __restrict__ bias,
        u16* __restrict__ outb, const u16* __restrict__ res, int Nf) {
    __shared__ __align__(16) u16 lW[2][32][64][8];   // [buf][kc][col][8] = 2 x 32 KB
    const int bm = blockIdx.x * 64;
    const int tid = threadIdx.x, lane = tid & 63, wave = tid >> 6;
    const int lr = lane & 15, lg = lane >> 4;
    const int wr = (wave >> 1) * 32;     // row half
    const int wc = (wave & 1) * 32;      // col half within chunk

    // A fragments from global: 16 x dwordx4, 64B contiguous per row -> coalesced
    short8v a_all[2][8];
    #pragma unroll
    for (int m = 0; m < 2; m++)
        #pragma unroll
        for (int s = 0; s < 8; s++)
            a_all[m][s] = *(const short8v*)(X + (size_t)(bm + wr + m * 16 + lr) * 256 + s * 32 + lg * 8);

    // stage chunk 0 (2048 x 16B)
    #pragma unroll
    for (int r = 0; r < 8; r++) {
        const int cb = r * 256 + wave * 64;     // wave-uniform base
        const int d  = cb + lane;
        const int kc = d >> 6, col = d & 63;
        gload16(W + (size_t)col * 256 + kc * 8, (const u16*)&lW[0][0][0][0] + (size_t)cb * 8);
    }
    __syncthreads();

    for (int j = 0; j < NJ; j++) {
        if (j + 1 < NJ) {     // async prefetch next chunk into other buffer
            #pragma unroll
            for (int r = 0; r < 8; r++) {
                const int cb = r * 256 + wave * 64;
                const int d  = cb + lane;
                const int kc = d >> 6, col = d & 63;
                gload16(W + (size_t)((j + 1) * 64 + col) * 256 + kc * 8,
                        (const u16*)&lW[(j + 1) & 1][0][0][0] + (size_t)cb * 8);
            }
        }
        const u16 (*lWc)[64][8] = lW[j & 1];
        float4v acc[2][2] = {};
        #pragma unroll
        for (int s = 0; s < 8; s++) {
            short8v b0 = *(const short8v*)&lWc[s * 4 + lg][wc + lr][0];
            short8v b1 = *(const short8v*)&lWc[s * 4 + lg][wc + 16 + lr][0];
            #pragma unroll
            for (int m = 0; m < 2; m++) {
                acc[m][0] = MFMA16(a_all[m][s], b0, acc[m][0]);
                acc[m][1] = MFMA16(a_all[m][s], b1, acc[m][1]);
            }
        }
        #pragma unroll
        for (int n = 0; n < 2; n++) {
            const int c = j * 64 + wc + n * 16 + lr;
            const float bv = bias[c];
            #pragma unroll
            for (int m = 0; m < 2; m++)
                #pragma unroll
                for (int rq = 0; rq < 4; rq++) {
                    const int row = bm + wr + m * 16 + lg * 4 + rq;
                    float v = acc[m][n][rq] + bv;
                    const size_t oidx = (size_t)row * Nf + c;
                    if (EPI == 1) v += bf2f(res[oidx]);
                    outb[oidx] = f2bf(v);
                }
        }
        __syncthreads();   // retires lW[j&1] reads; drains prefetch for j+1
    }
}

// ---- fused MLP: LN2 + fc1 + GELU + fc2 + residual; 64 rows/block, 68 KB LDS ----
__global__ __launch_bounds__(256) void mlp_fused(
        const u16* __restrict__ x2,
        const float* __restrict__ ln2w, const float* __restrict__ ln2b,
        const u16* __restrict__ w1, const float* __restrict__ b1,
        const u16* __restrict__ w2, const float* __restrict__ b2,
        float* __restrict__ out) {
    __shared__ __align__(16) u16 lX[32][64][8];    // 32 KB x3, frag order
    __shared__ __align__(16) u16 lW1[32][32][8];   // 16 KB w1 chunk [kc][hcol][8]
    __shared__ __align__(16) u16 lW2[4][256][8];   // 16 KB w2 chunk [kc][ocol][8]
    __shared__ __align__(16) u16 lH[4][64][8];     // 4 KB  h chunk  [kc][row][8]
    const int bm = blockIdx.x * 64;
    const int tid = threadIdx.x, lane = tid & 63, wave = tid >> 6;
    const int lr = lane & 15, lg = lane >> 4;
    const int wr  = (wave >> 1) * 32;    // row half
    const int wc1 = (wave & 1) * 16;     // fc1 col (within 32-chunk)
    const int wc2 = (wave & 1) * 128;    // fc2 col half

    // ---- LN2: x3 = LN(x2) -> lX ----
    {
        const int row = tid >> 2, q = tid & 3;
        const u16* rp = x2 + (size_t)(bm + row) * 256 + q * 64;
        uint4 rv[8];
        #pragma unroll
        for (int g = 0; g < 8; g++) rv[g] = ((const uint4*)rp)[g];
        float s = 0.f, sq = 0.f;
        #pragma unroll
        for (int g = 0; g < 8; g++) {
            const u16* e = (const u16*)&rv[g];
            #pragma unroll
            for (int t = 0; t < 8; t++) { float f = bf2f(e[t]); s += f; sq += f * f; }
        }
        s  += __shfl_xor(s, 1);  s  += __shfl_xor(s, 2);
        sq += __shfl_xor(sq, 1); sq += __shfl_xor(sq, 2);
        const float mean = s * (1.f / 256.f);
        const float rs = rsqrtf(sq * (1.f / 256.f) - mean * mean + 1e-5f);
        #pragma unroll
        for (int g = 0; g < 8; g++) {
            const int c0 = q * 64 + g * 8;
            float4 w4a = *(const float4*)(ln2w + c0), w4b = *(const float4*)(ln2w + c0 + 4);
            float4 b4a = *(const float4*)(ln2b + c0), b4b = *(const float4*)(ln2b + c0 + 4);
            const u16* e = (const u16*)&rv[g];
            u16 o[8];
            o[0] = f2bf((bf2f(e[0]) - mean) * rs * w4a.x + b4a.x);
            o[1] = f2bf((bf2f(e[1]) - mean) * rs * w4a.y + b4a.y);
            o[2] = f2bf((bf2f(e[2]) - mean) * rs * w4a.z + b4a.z);
            o[3] = f2bf((bf2f(e[3]) - mean) * rs * w4a.w + b4a.w);
            o[4] = f2bf((bf2f(e[4]) - mean) * rs * w4b.x + b4b.x);
            o[5] = f2bf((bf2f(e[5]) - mean) * rs * w4b.y + b4b.y);
            o[6] = f2bf((bf2f(e[6]) - mean) * rs * w4b.z + b4b.z);
            o[7] = f2bf((bf2f(e[7]) - mean) * rs * w4b.w + b4b.w);
            *(uint4*)&lX[c0 >> 3][row][0] = *(uint4*)o;
        }
    }
    // ---- stage chunk 0 weights (1024 x 16B each) ----
    #pragma unroll
    for (int r = 0; r < 4; r++) {
        const int cb = r * 256 + wave * 64;
        const int d  = cb + lane;
        const int kc = d >> 5, col = d & 31;
        gload16(w1 + (size_t)col * 256 + kc * 8, (const u16*)&lW1[0][0][0] + (size_t)cb * 8);
    }
    #pragma unroll
    for (int r = 0; r < 4; r++) {
        const int cb = r * 256 + wave * 64;
        const int d  = cb + lane;
        const int kc = d >> 8, col = d & 255;
        gload16(w2 + (size_t)col * 1024 + kc * 8, (const u16*)&lW2[0][0][0] + (size_t)cb * 8);
    }
    __syncthreads();

    // x3 A-fragments -> registers (reused all 32 chunks)
    short8v a_all[2][8];
    #pragma unroll
    for (int m = 0; m < 2; m++)
        #pragma unroll
        for (int s = 0; s < 8; s++)
            a_all[m][s] = *(const short8v*)&lX[s * 4 + lg][wr + m * 16 + lr][0];

    float4v acc_o[2][8] = {};
    for (int j = 0; j < 32; j++) {
        // ---- fc1: h[64][32] chunk ----
        float4v ah[2] = {};
        #pragma unroll
        for (int s = 0; s < 8; s++) {
            short8v b = *(const short8v*)&lW1[s * 4 + lg][wc1 + lr][0];
            ah[0] = MFMA16(a_all[0][s], b, ah[0]);
            ah[1] = MFMA16(a_all[1][s], b, ah[1]);
        }
        #pragma unroll
        for (int m = 0; m < 2; m++)
            #pragma unroll
            for (int rq = 0; rq < 4; rq++) {
                const int row = wr + m * 16 + lg * 4 + rq;
                const int c = wc1 + lr;
                float v = ah[m][rq] + b1[j * 32 + c];
                v = 0.5f * v * (1.f + erff(v * 0.70710678118654752f));
                lH[c >> 3][row][c & 7] = f2bf(v);
            }
        __syncthreads();   // A: lH ready; lW1(j) reads done; drains lW2(j) stage
        if (j + 1 < 32) {  // restage lW1 for j+1 (async, lands by barrier B)
            #pragma unroll
            for (int r = 0; r < 4; r++) {
                const int cb = r * 256 + wave * 64;
                const int d  = cb + lane;
                const int kc = d >> 5, col = d & 31;
                gload16(w1 + (size_t)((j + 1) * 32 + col) * 256 + kc * 8,
                        (const u16*)&lW1[0][0][0] + (size_t)cb * 8);
            }
        }
        // ---- fc2: out[64][256] += h_chunk @ w2_chunk^T ----
        short8v ha0 = *(const short8v*)&lH[lg][wr + lr][0];
        short8v ha1 = *(const short8v*)&lH[lg][wr + 16 + lr][0];
        #pragma unroll
        for (int n = 0; n < 8; n++) {
            short8v b = *(const short8v*)&lW2[lg][wc2 + n * 16 + lr][0];
            acc_o[0][n] = MFMA16(ha0, b, acc_o[0][n]);
            acc_o[1][n] = MFMA16(ha1, b, acc_o[1][n]);
        }
        __syncthreads();   // B: lW2(j)/lH reads done; drains lW1(j+1) stage
        if (j + 1 < 32) {  // restage lW2 for j+1 (async, lands by next barrier A)
            #pragma unroll
            for (int r = 0; r < 4; r++) {
                const int cb = r * 256 + wave * 64;
                const int d  = cb + lane;
                const int kc = d >> 8, col = d & 255;
                gload16(w2 + (size_t)col * 1024 + (j + 1) * 32 + kc * 8,
                        (const u16*)&lW2[0][0][0] + (size_t)cb * 8);
            }
        }
    }

    // ---- epilogue: out = x3 + fc2 + b2 (fp32) ----
    #pragma unroll
    for (int n = 0; n < 8; n++) {
        const int c = wc2 + n * 16 + lr;
        const float bv = b2[c];
        #pragma unroll
        for (int m = 0; m < 2; m++)
            #pragma unroll
            for (int rq = 0; rq < 4; rq++) {
                const int row = wr + m * 16 + lg * 4 + rq;
                const float xv = bf2f(lX[c >> 3][row][c & 7]);
                out[(size_t)(bm + row) * 256 + c] = acc_o[m][n][rq] + bv + xv;
            }
    }
}

// ---------------- MFMA attention: one block per (b,a), 4 waves, 8 heads ----------------
__global__ __launch_bounds__(256) void attn_mfma(
        const u16* __restrict__ qkv, const unsigned char* __restrict__ mask,
        u16* __restrict__ out) {
    __shared__ u16 sk[128][32];
    __shared__ u16 svt[32][136];
    __shared__ u16 sp[4][32][136];
    __shared__ unsigned char smask[128];
    const int ba = blockIdx.x;
    const size_t rowbase = (size_t)ba * Tc;
    const int tid  = threadIdx.x;
    const int lane = tid & 63;
    const int wave = tid >> 6;
    const int wq0  = wave * 32;
    const int lrow = lane & 15, lg = lane >> 4;
    if (tid < 128) smask[tid] = mask[rowbase + tid];

    const float scale  = 0.17677669529663687f;
    const float inv128 = 1.0f / 128.0f;
    const float4v zero4 = {0.f, 0.f, 0.f, 0.f};

    for (int h = 0; h < Hc; h++) {
        {
            const int r = tid >> 1, half = tid & 1;
            const u16* gbase = qkv + (rowbase + r) * 768 + h * 32 + half * 16;
            uint4 k0 = *(const uint4*)(gbase + 256);
            uint4 k1 = *(const uint4*)(gbase + 256 + 8);
            *(uint4*)&sk[r][half * 16]     = k0;
            *(uint4*)&sk[r][half * 16 + 8] = k1;
            uint4 v0 = *(const uint4*)(gbase + 512);
            uint4 v1 = *(const uint4*)(gbase + 512 + 8);
            u16 vt[16];
            *(uint4*)&vt[0] = v0; *(uint4*)&vt[8] = v1;
            #pragma unroll
            for (int e = 0; e < 16; e++) svt[half * 16 + e][r] = vt[e];
        }
        __syncthreads();

        short8v a0, a1;
        {
            const u16* qp0 = qkv + (rowbase + wq0 + lrow) * 768 + h * 32 + lg * 8;
            const u16* qp1 = qp0 + 16 * 768;
            a0 = *(const short8v*)qp0;
            a1 = *(const short8v*)qp1;
        }
        float4v s_acc[2][8];
        #pragma unroll
        for (int j = 0; j < 8; j++) {
            short8v bj = *(const short8v*)&sk[j * 16 + lrow][lg * 8];
            s_acc[0][j] = MFMA16(a0, bj, zero4);
            s_acc[1][j] = MFMA16(a1, bj, zero4);
        }

        #pragma unroll
        for (int i = 0; i < 2; i++) {
            #pragma unroll
            for (int r = 0; r < 4; r++) {
                float m = s_acc[i][0][r];
                #pragma unroll
                for (int j = 1; j < 8; j++) m = fmaxf(m, s_acc[i][j][r]);
                #pragma unroll
                for (int off = 1; off < 16; off <<= 1) m = fmaxf(m, __shfl_xor(m, off));
                float sum = 0.f;
                #pragma unroll
                for (int j = 0; j < 8; j++) {
                    float e = __expf((s_acc[i][j][r] - m) * scale);
                    sum += e;
                    s_acc[i][j][r] = e;
                }
                #pragma unroll
                for (int off = 1; off < 16; off <<= 1) sum += __shfl_xor(sum, off);
                const int qloc = i * 16 + lg * 4 + r;
                const bool mk = smask[wq0 + qloc] != 0;
                const float invs = 1.f / sum;
                #pragma unroll
                for (int j = 0; j < 8; j++) {
                    float pv = mk ? inv128 : s_acc[i][j][r] * invs;
                    sp[wave][qloc][j * 16 + lrow] = f2bf(pv);
                }
            }
        }

        float4v o_acc[2][2] = {};
        #pragma unroll
        for (int t = 0; t < 4; t++) {
            short8v pa0 = *(const short8v*)&sp[wave][lrow][t * 32 + lg * 8];
            short8v pa1 = *(const short8v*)&sp[wave][16 + lrow][t * 32 + lg * 8];
            short8v vb0 = *(const short8v*)&svt[lrow][t * 32 + lg * 8];
            short8v vb1 = *(const short8v*)&svt[16 + lrow][t * 32 + lg * 8];
            o_acc[0][0] = MFMA16(pa0, vb0, o_acc[0][0]);
            o_acc[0][1] = MFMA16(pa0, vb1, o_acc[0][1]);
            o_acc[1][0] = MFMA16(pa1, vb0, o_acc[1][0]);
            o_acc[1][1] = MFMA16(pa1, vb1, o_acc[1][1]);
        }

        #pragma unroll
        for (int i = 0; i < 2; i++)
            #pragma unroll
            for (int n = 0; n < 2; n++)
                #pragma unroll
                for (int r = 0; r < 4; r++) {
                    size_t row = rowbase + wq0 + i * 16 + lg * 4 + r;
                    int col = h * 32 + n * 16 + lrow;
                    out[row * 256 + col] = f2bf(o_acc[i][n][r]);
                }
        __syncthreads();
    }
}

extern "C" void kernel_launch(void* const* d_in, const int* in_sizes, int n_in,
                              void* d_out, int out_size, void* d_ws, size_t ws_size,
                              hipStream_t stream) {
    const float* x      = (const float*)d_in[0];
    const unsigned char* mask = (const unsigned char*)d_in[1];
    const float* ln1_w  = (const float*)d_in[2];
    const float* ln1_b  = (const float*)d_in[3];
    const float* qkv_w  = (const float*)d_in[4];
    const float* qkv_b  = (const float*)d_in[5];
    const float* proj_w = (const float*)d_in[6];
    const float* proj_b = (const float*)d_in[7];
    const float* ln2_w  = (const float*)d_in[8];
    const float* ln2_b  = (const float*)d_in[9];
    const float* fc1_w  = (const float*)d_in[10];
    const float* fc1_b  = (const float*)d_in[11];
    const float* fc2_w  = (const float*)d_in[12];
    const float* fc2_b  = (const float*)d_in[13];
    float* out = (float*)d_out;

    char* ws = (char*)d_ws;
    size_t off = 0;
    auto alloc = [&](size_t elems) -> u16* {
        u16* p = (u16*)(ws + off);
        off += ((elems * 2 + 255) / 256) * 256;
        return p;
    };
    u16* wqb  = alloc(768 * 256);
    u16* wpb  = alloc(256 * 256);
    u16* w1b  = alloc(1024 * 256);
    u16* w2b  = alloc(256 * 1024);
    u16* x1b  = alloc((size_t)NROW * Cc);
    u16* qkvb = alloc((size_t)NROW * 3 * Cc);
    u16* attb = alloc((size_t)NROW * Cc);
    u16* x2b  = alloc((size_t)NROW * Cc);

    cast4_kernel<<<(786432 + 255) / 256, 256, 0, stream>>>(
        qkv_w, 196608, proj_w, 65536, fc1_w, 262144, fc2_w, 262144,
        wqb, wpb, w1b, w2b);
    ln_f32<<<NROW / 4, 256, 0, stream>>>(x, ln1_w, ln1_b, x1b);
    gemm_breg<12, 0><<<NROW / 64, 256, 0, stream>>>(
        x1b, wqb, qkv_b, qkvb, nullptr, 768);
    attn_mfma<<<Bc * Ac, 256, 0, stream>>>(qkvb, mask, attb);
    gemm_breg<4, 1><<<NROW / 64, 256, 0, stream>>>(
        attb, wpb, proj_b, x2b, x1b, 256);
    mlp_fused<<<NROW / 64, 256, 0, stream>>>(
        x2b, ln2_w, ln2_b, w1b, fc1_b, w2b, fc2_b, out);
}

// Round 7
// 414.718 us; speedup vs baseline: 1.1651x; 1.1651x over previous
//
#include <hip/hip_runtime.h>
#include <hip/hip_bf16.h>

typedef unsigned short u16;
typedef unsigned int   u32;

static constexpr int Bc = 8, Ac = 64, Tc = 128, Cc = 256, Hc = 8;
static constexpr int NROW = Bc * Ac * Tc;   // 65536 tokens
static constexpr int DH = Cc / Hc;          // 32

__device__ __forceinline__ float bf2f(u16 h) {
    u32 u = ((u32)h) << 16; float f; __builtin_memcpy(&f, &u, 4); return f;
}
__device__ __forceinline__ u16 f2bf(float f) {
    u32 u; __builtin_memcpy(&u, &f, 4);
    u += 0x7fffu + ((u >> 16) & 1u);   // RNE
    return (u16)(u >> 16);
}

typedef __attribute__((ext_vector_type(8))) short  short8v;
typedef __attribute__((ext_vector_type(4))) float  float4v;

__device__ __forceinline__ void gload16(const void* g, const void* lds) {
    __builtin_amdgcn_global_load_lds(
        (const __attribute__((address_space(1))) void*)g,
        (__attribute__((address_space(3))) void*)lds, 16, 0, 0);
}

#define MFMA16(a, b, c) __builtin_amdgcn_mfma_f32_16x16x32_bf16((a), (b), (c), 0, 0, 0)

// ---------------- cast all weights fp32 -> bf16, one launch ----------------
__global__ void cast4_kernel(const float* __restrict__ a, int na,
                             const float* __restrict__ b, int nb,
                             const float* __restrict__ c, int nc,
                             const float* __restrict__ d, int nd,
                             u16* oa, u16* ob, u16* oc, u16* od) {
    int i = blockIdx.x * 256 + threadIdx.x;
    if (i < na) { oa[i] = f2bf(a[i]); return; }
    i -= na;
    if (i < nb) { ob[i] = f2bf(b[i]); return; }
    i -= nb;
    if (i < nc) { oc[i] = f2bf(c[i]); return; }
    i -= nc;
    if (i < nd) { od[i] = f2bf(d[i]); }
}

// ---------------- LayerNorm, fp32 input -> bf16 out ----------------
__global__ __launch_bounds__(256) void ln_f32(const float* __restrict__ in,
        const float* __restrict__ w, const float* __restrict__ b,
        u16* __restrict__ out) {
    int row  = blockIdx.x * 4 + (threadIdx.x >> 6);
    int lane = threadIdx.x & 63;
    const float* rp = in + (size_t)row * Cc + lane * 4;
    float4 v = *(const float4*)rp;
    float s  = v.x + v.y + v.z + v.w;
    float sq = v.x * v.x + v.y * v.y + v.z * v.z + v.w * v.w;
    for (int off = 32; off; off >>= 1) { s += __shfl_xor(s, off); sq += __shfl_xor(sq, off); }
    float mean = s * (1.f / Cc);
    float rs = rsqrtf(sq * (1.f / Cc) - mean * mean + 1e-5f);
    int c0 = lane * 4;
    float vv[4] = {v.x, v.y, v.z, v.w};
    ushort4 ov;
    ov.x = f2bf((vv[0] - mean) * rs * w[c0 + 0] + b[c0 + 0]);
    ov.y = f2bf((vv[1] - mean) * rs * w[c0 + 1] + b[c0 + 1]);
    ov.z = f2bf((vv[2] - mean) * rs * w[c0 + 2] + b[c0 + 2]);
    ov.w = f2bf((vv[3] - mean) * rs * w[c0 + 3] + b[c0 + 3]);
    *(ushort4*)(out + (size_t)row * Cc + c0) = ov;
}

// ---------------- LayerNorm, bf16 input -> bf16 out ----------------
__global__ __launch_bounds__(256) void ln_bf16(const u16* __restrict__ in,
        const float* __restrict__ w, const float* __restrict__ b,
        u16* __restrict__ out) {
    int row  = blockIdx.x * 4 + (threadIdx.x >> 6);
    int lane = threadIdx.x & 63;
    const u16* rp = in + (size_t)row * Cc + lane * 4;
    ushort4 hv = *(const ushort4*)rp;
    float vv[4] = {bf2f(hv.x), bf2f(hv.y), bf2f(hv.z), bf2f(hv.w)};
    float s = vv[0] + vv[1] + vv[2] + vv[3];
    float sq = vv[0]*vv[0] + vv[1]*vv[1] + vv[2]*vv[2] + vv[3]*vv[3];
    for (int off = 32; off; off >>= 1) { s += __shfl_xor(s, off); sq += __shfl_xor(sq, off); }
    float mean = s * (1.f / Cc);
    float rs = rsqrtf(sq * (1.f / Cc) - mean * mean + 1e-5f);
    int c0 = lane * 4;
    ushort4 ov;
    ov.x = f2bf((vv[0] - mean) * rs * w[c0 + 0] + b[c0 + 0]);
    ov.y = f2bf((vv[1] - mean) * rs * w[c0 + 1] + b[c0 + 1]);
    ov.z = f2bf((vv[2] - mean) * rs * w[c0 + 2] + b[c0 + 2]);
    ov.w = f2bf((vv[3] - mean) * rs * w[c0 + 3] + b[c0 + 3]);
    *(ushort4*)(out + (size_t)row * Cc + c0) = ov;
}

// ------- GEMM 128x128, double-buffered 2-phase (T3), XCD-swizzled (m204) -------
// out[M][Nf] = X[M][K] @ W[Nf][K]^T; 1-D grid, lid -> (bm = lid/nbn, bn = lid%nbn).
// EPI: 0 bias->bf16 | 1 bias+res->bf16 | 2 bias+GELU->bf16 | 3 bias+res->fp32
template<int K, int EPI>
__global__ __launch_bounds__(256) void gemm128(
        const u16* __restrict__ X, const u16* __restrict__ W,
        const float* __restrict__ bias,
        u16* __restrict__ outb, float* __restrict__ outf,
        const u16* __restrict__ res, int Nf, int nbn) {
    __shared__ __align__(16) u16 lA[2][4][128][8];   // 2 x 8 KB
    __shared__ __align__(16) u16 lB[2][4][128][8];
    // bijective XCD swizzle (nwg % 8 == 0 for all our launches):
    // consecutive lid share bm (A-panel) and land on the same XCD.
    const int nwg = gridDim.x;
    const int q8  = nwg >> 3;
    const int lid = (blockIdx.x & 7) * q8 + (blockIdx.x >> 3);
    const int bn  = (lid % nbn) * 128;
    const int bm  = (lid / nbn) * 128;
    const int tid = threadIdx.x, lane = tid & 63, wave = tid >> 6;
    const int wr = (wave >> 1) * 64, wc = (wave & 1) * 64;   // wave's 64x64 sub-tile
    const int lr = lane & 15, lg = lane >> 4;

    auto stage = [&](int k0, int buf) {
        #pragma unroll
        for (int qq = 0; qq < 2; qq++) {
            const int cbase = wave * 128 + qq * 64;   // wave-uniform LDS base
            const int c  = cbase + lane;
            const int row = c & 127, kc = c >> 7;
            gload16(X + (size_t)(bm + row) * K + k0 + kc * 8,
                    (const u16*)&lA[buf][0][0][0] + (size_t)cbase * 8);
            gload16(W + (size_t)(bn + row) * K + k0 + kc * 8,
                    (const u16*)&lB[buf][0][0][0] + (size_t)cbase * 8);
        }
    };

    stage(0, 0);
    __syncthreads();   // compiler drains vmcnt before s_barrier

    float4v acc[4][4] = {};
    int cur = 0;
    for (int k0 = 0; k0 < K; k0 += 32) {
        if (k0 + 32 < K) stage(k0 + 32, cur ^ 1);   // issue BEFORE compute (T3)
        short8v a[4], b[4];
        #pragma unroll
        for (int i = 0; i < 4; i++) a[i] = *(const short8v*)&lA[cur][lg][wr + i * 16 + lr][0];
        #pragma unroll
        for (int j = 0; j < 4; j++) b[j] = *(const short8v*)&lB[cur][lg][wc + j * 16 + lr][0];
        #pragma unroll
        for (int i = 0; i < 4; i++)
            #pragma unroll
            for (int j = 0; j < 4; j++)
                acc[i][j] = MFMA16(a[i], b[j], acc[i][j]);
        __syncthreads();   // one barrier/step: drains next-buf loads (landed under MFMA)
        cur ^= 1;
    }

    // C/D layout: col = lane&15, row = (lane>>4)*4 + reg
    const int rr = lg * 4, cc0 = lr;
    #pragma unroll
    for (int i = 0; i < 4; i++)
        #pragma unroll
        for (int j = 0; j < 4; j++) {
            int c = bn + wc + j * 16 + cc0;
            float bv = bias[c];
            #pragma unroll
            for (int r4 = 0; r4 < 4; r4++) {
                int r = bm + wr + i * 16 + rr + r4;
                float v = acc[i][j][r4] + bv;
                size_t oidx = (size_t)r * Nf + c;
                if (EPI == 1) v += bf2f(res[oidx]);
                if (EPI == 2) v = 0.5f * v * (1.f + erff(v * 0.70710678118654752f));
                if (EPI == 3) {
                    outf[oidx] = v + bf2f(res[oidx]);
                } else {
                    outb[oidx] = f2bf(v);
                }
            }
        }
}

// ---------------- MFMA attention: one block per (b,a), 4 waves, 8 heads ----------------
__global__ __launch_bounds__(256) void attn_mfma(
        const u16* __restrict__ qkv, const unsigned char* __restrict__ mask,
        u16* __restrict__ out) {
    __shared__ u16 sk[128][32];
    __shared__ u16 svt[32][136];
    __shared__ u16 sp[4][32][136];
    __shared__ unsigned char smask[128];
    const int ba = blockIdx.x;
    const size_t rowbase = (size_t)ba * Tc;
    const int tid  = threadIdx.x;
    const int lane = tid & 63;
    const int wave = tid >> 6;
    const int wq0  = wave * 32;
    const int lrow = lane & 15, lg = lane >> 4;
    if (tid < 128) smask[tid] = mask[rowbase + tid];

    const float scale  = 0.17677669529663687f;
    const float inv128 = 1.0f / 128.0f;
    const float4v zero4 = {0.f, 0.f, 0.f, 0.f};

    for (int h = 0; h < Hc; h++) {
        {
            const int r = tid >> 1, half = tid & 1;
            const u16* gbase = qkv + (rowbase + r) * 768 + h * 32 + half * 16;
            uint4 k0 = *(const uint4*)(gbase + 256);
            uint4 k1 = *(const uint4*)(gbase + 256 + 8);
            *(uint4*)&sk[r][half * 16]     = k0;
            *(uint4*)&sk[r][half * 16 + 8] = k1;
            uint4 v0 = *(const uint4*)(gbase + 512);
            uint4 v1 = *(const uint4*)(gbase + 512 + 8);
            u16 vt[16];
            *(uint4*)&vt[0] = v0; *(uint4*)&vt[8] = v1;
            #pragma unroll
            for (int e = 0; e < 16; e++) svt[half * 16 + e][r] = vt[e];
        }
        __syncthreads();

        short8v a0, a1;
        {
            const u16* qp0 = qkv + (rowbase + wq0 + lrow) * 768 + h * 32 + lg * 8;
            const u16* qp1 = qp0 + 16 * 768;
            a0 = *(const short8v*)qp0;
            a1 = *(const short8v*)qp1;
        }
        float4v s_acc[2][8];
        #pragma unroll
        for (int j = 0; j < 8; j++) {
            short8v bj = *(const short8v*)&sk[j * 16 + lrow][lg * 8];
            s_acc[0][j] = MFMA16(a0, bj, zero4);
            s_acc[1][j] = MFMA16(a1, bj, zero4);
        }

        #pragma unroll
        for (int i = 0; i < 2; i++) {
            #pragma unroll
            for (int r = 0; r < 4; r++) {
                float m = s_acc[i][0][r];
                #pragma unroll
                for (int j = 1; j < 8; j++) m = fmaxf(m, s_acc[i][j][r]);
                #pragma unroll
                for (int off = 1; off < 16; off <<= 1) m = fmaxf(m, __shfl_xor(m, off));
                float sum = 0.f;
                #pragma unroll
                for (int j = 0; j < 8; j++) {
                    float e = __expf((s_acc[i][j][r] - m) * scale);
                    sum += e;
                    s_acc[i][j][r] = e;
                }
                #pragma unroll
                for (int off = 1; off < 16; off <<= 1) sum += __shfl_xor(sum, off);
                const int qloc = i * 16 + lg * 4 + r;
                const bool mk = smask[wq0 + qloc] != 0;
                const float invs = 1.f / sum;
                #pragma unroll
                for (int j = 0; j < 8; j++) {
                    float pv = mk ? inv128 : s_acc[i][j][r] * invs;
                    sp[wave][qloc][j * 16 + lrow] = f2bf(pv);
                }
            }
        }

        float4v o_acc[2][2] = {};
        #pragma unroll
        for (int t = 0; t < 4; t++) {
            short8v pa0 = *(const short8v*)&sp[wave][lrow][t * 32 + lg * 8];
            short8v pa1 = *(const short8v*)&sp[wave][16 + lrow][t * 32 + lg * 8];
            short8v vb0 = *(const short8v*)&svt[lrow][t * 32 + lg * 8];
            short8v vb1 = *(const short8v*)&svt[16 + lrow][t * 32 + lg * 8];
            o_acc[0][0] = MFMA16(pa0, vb0, o_acc[0][0]);
            o_acc[0][1] = MFMA16(pa0, vb1, o_acc[0][1]);
            o_acc[1][0] = MFMA16(pa1, vb0, o_acc[1][0]);
            o_acc[1][1] = MFMA16(pa1, vb1, o_acc[1][1]);
        }

        #pragma unroll
        for (int i = 0; i < 2; i++)
            #pragma unroll
            for (int n = 0; n < 2; n++)
                #pragma unroll
                for (int r = 0; r < 4; r++) {
                    size_t row = rowbase + wq0 + i * 16 + lg * 4 + r;
                    int col = h * 32 + n * 16 + lrow;
                    out[row * 256 + col] = f2bf(o_acc[i][n][r]);
                }
        __syncthreads();
    }
}

extern "C" void kernel_launch(void* const* d_in, const int* in_sizes, int n_in,
                              void* d_out, int out_size, void* d_ws, size_t ws_size,
                              hipStream_t stream) {
    const float* x      = (const float*)d_in[0];
    const unsigned char* mask = (const unsigned char*)d_in[1];
    const float* ln1_w  = (const float*)d_in[2];
    const float* ln1_b  = (const float*)d_in[3];
    const float* qkv_w  = (const float*)d_in[4];
    const float* qkv_b  = (const float*)d_in[5];
    const float* proj_w = (const float*)d_in[6];
    const float* proj_b = (const float*)d_in[7];
    const float* ln2_w  = (const float*)d_in[8];
    const float* ln2_b  = (const float*)d_in[9];
    const float* fc1_w  = (const float*)d_in[10];
    const float* fc1_b  = (const float*)d_in[11];
    const float* fc2_w  = (const float*)d_in[12];
    const float* fc2_b  = (const float*)d_in[13];
    float* out = (float*)d_out;

    char* ws = (char*)d_ws;
    size_t off = 0;
    auto alloc = [&](size_t elems) -> u16* {
        u16* p = (u16*)(ws + off);
        off += ((elems * 2 + 255) / 256) * 256;
        return p;
    };
    u16* wqb  = alloc(768 * 256);
    u16* wpb  = alloc(256 * 256);
    u16* w1b  = alloc(1024 * 256);
    u16* w2b  = alloc(256 * 1024);
    u16* x1b  = alloc((size_t)NROW * Cc);
    u16* qkvb = alloc((size_t)NROW * 3 * Cc);
    u16* attb = alloc((size_t)NROW * Cc);
    u16* x2b  = alloc((size_t)NROW * Cc);
    u16* hb   = qkvb;   // fc1 output reuses qkv(3NC)+attn(NC) region = 4NC
    u16* x3b  = x1b;    // x3 reuses x1 region (x1 dead after proj)

    cast4_kernel<<<(786432 + 255) / 256, 256, 0, stream>>>(
        qkv_w, 196608, proj_w, 65536, fc1_w, 262144, fc2_w, 262144,
        wqb, wpb, w1b, w2b);
    ln_f32<<<NROW / 4, 256, 0, stream>>>(x, ln1_w, ln1_b, x1b);
    // qkv: M=65536, N=768, K=256  -> nwg = 512*6
    gemm128<256, 0><<<512 * 6, 256, 0, stream>>>(
        x1b, wqb, qkv_b, qkvb, nullptr, nullptr, 768, 6);
    attn_mfma<<<Bc * Ac, 256, 0, stream>>>(qkvb, mask, attb);
    // proj + residual(x1): N=256 -> nwg = 512*2
    gemm128<256, 1><<<512 * 2, 256, 0, stream>>>(
        attb, wpb, proj_b, x2b, nullptr, x1b, 256, 2);
    ln_bf16<<<NROW / 4, 256, 0, stream>>>(x2b, ln2_w, ln2_b, x3b);
    // fc1 + GELU: N=1024 -> nwg = 512*8
    gemm128<256, 2><<<512 * 8, 256, 0, stream>>>(
        x3b, w1b, fc1_b, hb, nullptr, nullptr, 1024, 8);
    // fc2 + residual(x3) -> fp32 out: N=256, K=1024 -> nwg = 512*2
    gemm128<1024, 3><<<512 * 2, 256, 0, stream>>>(
        hb, w2b, fc2_b, nullptr, out, x3b, 256, 2);
}

// Round 8
// 391.029 us; speedup vs baseline: 1.2356x; 1.0606x over previous
//
#include <hip/hip_runtime.h>
#include <hip/hip_bf16.h>

typedef unsigned short u16;
typedef unsigned int   u32;

static constexpr int Bc = 8, Ac = 64, Tc = 128, Cc = 256, Hc = 8;
static constexpr int NROW = Bc * Ac * Tc;   // 65536 tokens
static constexpr int DH = Cc / Hc;          // 32

__device__ __forceinline__ float bf2f(u16 h) {
    u32 u = ((u32)h) << 16; float f; __builtin_memcpy(&f, &u, 4); return f;
}
__device__ __forceinline__ u16 f2bf(float f) {
    u32 u; __builtin_memcpy(&u, &f, 4);
    u += 0x7fffu + ((u >> 16) & 1u);   // RNE
    return (u16)(u >> 16);
}

typedef __attribute__((ext_vector_type(8))) short  short8v;
typedef __attribute__((ext_vector_type(4))) float  float4v;

__device__ __forceinline__ void gload16(const void* g, const void* lds) {
    __builtin_amdgcn_global_load_lds(
        (const __attribute__((address_space(1))) void*)g,
        (__attribute__((address_space(3))) void*)lds, 16, 0, 0);
}

#define MFMA16(a, b, c) __builtin_amdgcn_mfma_f32_16x16x32_bf16((a), (b), (c), 0, 0, 0)

// ---------------- cast all weights fp32 -> bf16, one launch ----------------
__global__ void cast4_kernel(const float* __restrict__ a, int na,
                             const float* __restrict__ b, int nb,
                             const float* __restrict__ c, int nc,
                             const float* __restrict__ d, int nd,
                             u16* oa, u16* ob, u16* oc, u16* od) {
    int i = blockIdx.x * 256 + threadIdx.x;
    if (i < na) { oa[i] = f2bf(a[i]); return; }
    i -= na;
    if (i < nb) { ob[i] = f2bf(b[i]); return; }
    i -= nb;
    if (i < nc) { oc[i] = f2bf(c[i]); return; }
    i -= nc;
    if (i < nd) { od[i] = f2bf(d[i]); }
}

// ---------------- LayerNorm, fp32 input -> bf16 out ----------------
__global__ __launch_bounds__(256) void ln_f32(const float* __restrict__ in,
        const float* __restrict__ w, const float* __restrict__ b,
        u16* __restrict__ out) {
    int row  = blockIdx.x * 4 + (threadIdx.x >> 6);
    int lane = threadIdx.x & 63;
    const float* rp = in + (size_t)row * Cc + lane * 4;
    float4 v = *(const float4*)rp;
    float s  = v.x + v.y + v.z + v.w;
    float sq = v.x * v.x + v.y * v.y + v.z * v.z + v.w * v.w;
    for (int off = 32; off; off >>= 1) { s += __shfl_xor(s, off); sq += __shfl_xor(sq, off); }
    float mean = s * (1.f / Cc);
    float rs = rsqrtf(sq * (1.f / Cc) - mean * mean + 1e-5f);
    int c0 = lane * 4;
    float vv[4] = {v.x, v.y, v.z, v.w};
    ushort4 ov;
    ov.x = f2bf((vv[0] - mean) * rs * w[c0 + 0] + b[c0 + 0]);
    ov.y = f2bf((vv[1] - mean) * rs * w[c0 + 1] + b[c0 + 1]);
    ov.z = f2bf((vv[2] - mean) * rs * w[c0 + 2] + b[c0 + 2]);
    ov.w = f2bf((vv[3] - mean) * rs * w[c0 + 3] + b[c0 + 3]);
    *(ushort4*)(out + (size_t)row * Cc + c0) = ov;
}

// ---------------- LayerNorm, bf16 input -> bf16 out ----------------
__global__ __launch_bounds__(256) void ln_bf16(const u16* __restrict__ in,
        const float* __restrict__ w, const float* __restrict__ b,
        u16* __restrict__ out) {
    int row  = blockIdx.x * 4 + (threadIdx.x >> 6);
    int lane = threadIdx.x & 63;
    const u16* rp = in + (size_t)row * Cc + lane * 4;
    ushort4 hv = *(const ushort4*)rp;
    float vv[4] = {bf2f(hv.x), bf2f(hv.y), bf2f(hv.z), bf2f(hv.w)};
    float s = vv[0] + vv[1] + vv[2] + vv[3];
    float sq = vv[0]*vv[0] + vv[1]*vv[1] + vv[2]*vv[2] + vv[3]*vv[3];
    for (int off = 32; off; off >>= 1) { s += __shfl_xor(s, off); sq += __shfl_xor(sq, off); }
    float mean = s * (1.f / Cc);
    float rs = rsqrtf(sq * (1.f / Cc) - mean * mean + 1e-5f);
    int c0 = lane * 4;
    ushort4 ov;
    ov.x = f2bf((vv[0] - mean) * rs * w[c0 + 0] + b[c0 + 0]);
    ov.y = f2bf((vv[1] - mean) * rs * w[c0 + 1] + b[c0 + 1]);
    ov.z = f2bf((vv[2] - mean) * rs * w[c0 + 2] + b[c0 + 2]);
    ov.w = f2bf((vv[3] - mean) * rs * w[c0 + 3] + b[c0 + 3]);
    *(ushort4*)(out + (size_t)row * Cc + c0) = ov;
}

// ---- A-resident GEMM: out[128-rows/block][Nf] = X[.][256] @ W[Nf][256]^T ----
// 512 threads, 8 waves (4 M-groups x 2 N-groups). A staged once in LDS, A-frags
// hoisted to regs; weights streamed in 64-col chunks, double-buffered, ONE
// barrier per chunk. EPI: 0 bias->bf16 | 1 bias+res->bf16 | 2 bias+GELU->bf16
template<int NJ, int EPI>
__global__ __launch_bounds__(512) void gemm_ares(
        const u16* __restrict__ X, const u16* __restrict__ W,
        const float* __restrict__ bias,
        u16* __restrict__ outb, const u16* __restrict__ res, int Nf) {
    __shared__ __align__(16) u16 lA[32][128][8];      // 64 KB: full A tile, frag order
    __shared__ __align__(16) u16 lW[2][32][64][8];    // 2 x 32 KB: weight chunk dbuf
    const int bm   = blockIdx.x * 128;
    const int tid  = threadIdx.x, lane = tid & 63, wave = tid >> 6;
    const int lr   = lane & 15,  lg   = lane >> 4;
    const int wr   = (wave >> 1) * 32;   // 4 M-groups of 32 rows
    const int wc   = (wave & 1) * 32;    // 2 N-groups of 32 cols

    // prologue: stage A (4096 chunks) + first weight chunk (2048 chunks)
    #pragma unroll
    for (int r = 0; r < 8; r++) {
        const int cb = r * 512 + wave * 64;           // wave-uniform
        const int d  = cb + lane;
        const int kc = d >> 7, row = d & 127;
        gload16(X + (size_t)(bm + row) * 256 + kc * 8, (const u16*)lA + (size_t)cb * 8);
    }
    #pragma unroll
    for (int r = 0; r < 4; r++) {
        const int cb = r * 512 + wave * 64;
        const int d  = cb + lane;
        const int kc = d >> 6, row = d & 63;
        gload16(W + (size_t)row * 256 + kc * 8, (const u16*)&lW[0][0][0][0] + (size_t)cb * 8);
    }
    __syncthreads();

    // hoist A fragments: 16 ds_read_b128, reused across all chunks
    short8v a_all[8][2];
    #pragma unroll
    for (int s = 0; s < 8; s++) {
        a_all[s][0] = *(const short8v*)&lA[s * 4 + lg][wr + lr][0];
        a_all[s][1] = *(const short8v*)&lA[s * 4 + lg][wr + 16 + lr][0];
    }

    for (int j = 0; j < NJ; j++) {
        if (j + 1 < NJ) {   // prefetch next weight chunk into other buffer (async)
            #pragma unroll
            for (int r = 0; r < 4; r++) {
                const int cb = r * 512 + wave * 64;
                const int d  = cb + lane;
                const int kc = d >> 6, row = d & 63;
                gload16(W + (size_t)((j + 1) * 64 + row) * 256 + kc * 8,
                        (const u16*)&lW[(j + 1) & 1][0][0][0] + (size_t)cb * 8);
            }
        }
        const u16 (*lWc)[64][8] = lW[j & 1];
        float4v acc[2][2] = {};
        #pragma unroll
        for (int s = 0; s < 8; s++) {
            short8v b0 = *(const short8v*)&lWc[s * 4 + lg][wc + lr][0];
            short8v b1 = *(const short8v*)&lWc[s * 4 + lg][wc + 16 + lr][0];
            acc[0][0] = MFMA16(a_all[s][0], b0, acc[0][0]);
            acc[0][1] = MFMA16(a_all[s][0], b1, acc[0][1]);
            acc[1][0] = MFMA16(a_all[s][1], b0, acc[1][0]);
            acc[1][1] = MFMA16(a_all[s][1], b1, acc[1][1]);
        }
        // epilogue for this 128x64 chunk
        #pragma unroll
        for (int jj = 0; jj < 2; jj++) {
            const int c = j * 64 + wc + jj * 16 + lr;
            const float bv = bias[c];
            #pragma unroll
            for (int i = 0; i < 2; i++)
                #pragma unroll
                for (int rq = 0; rq < 4; rq++) {
                    const int row = bm + wr + i * 16 + lg * 4 + rq;
                    float v = acc[i][jj][rq] + bv;
                    const size_t oidx = (size_t)row * Nf + c;
                    if (EPI == 1) v += bf2f(res[oidx]);
                    if (EPI == 2) v = 0.5f * v * (1.f + erff(v * 0.70710678118654752f));
                    outb[oidx] = f2bf(v);
                }
        }
        __syncthreads();   // retires lW[j&1] reads; drains prefetch (landed under compute)
    }
}

// ------- GEMM 128x128, double-buffered 2-phase, XCD-swizzled (fc2: K=1024) -------
// EPI: 3 bias+res->fp32
template<int K, int EPI>
__global__ __launch_bounds__(256) void gemm128(
        const u16* __restrict__ X, const u16* __restrict__ W,
        const float* __restrict__ bias,
        u16* __restrict__ outb, float* __restrict__ outf,
        const u16* __restrict__ res, int Nf, int nbn) {
    __shared__ __align__(16) u16 lA[2][4][128][8];   // 2 x 8 KB
    __shared__ __align__(16) u16 lB[2][4][128][8];
    const int nwg = gridDim.x;
    const int q8  = nwg >> 3;
    const int lid = (blockIdx.x & 7) * q8 + (blockIdx.x >> 3);
    const int bn  = (lid % nbn) * 128;
    const int bm  = (lid / nbn) * 128;
    const int tid = threadIdx.x, lane = tid & 63, wave = tid >> 6;
    const int wr = (wave >> 1) * 64, wc = (wave & 1) * 64;
    const int lr = lane & 15, lg = lane >> 4;

    auto stage = [&](int k0, int buf) {
        #pragma unroll
        for (int qq = 0; qq < 2; qq++) {
            const int cbase = wave * 128 + qq * 64;
            const int c  = cbase + lane;
            const int row = c & 127, kc = c >> 7;
            gload16(X + (size_t)(bm + row) * K + k0 + kc * 8,
                    (const u16*)&lA[buf][0][0][0] + (size_t)cbase * 8);
            gload16(W + (size_t)(bn + row) * K + k0 + kc * 8,
                    (const u16*)&lB[buf][0][0][0] + (size_t)cbase * 8);
        }
    };

    stage(0, 0);
    __syncthreads();

    float4v acc[4][4] = {};
    int cur = 0;
    for (int k0 = 0; k0 < K; k0 += 32) {
        if (k0 + 32 < K) stage(k0 + 32, cur ^ 1);
        short8v a[4], b[4];
        #pragma unroll
        for (int i = 0; i < 4; i++) a[i] = *(const short8v*)&lA[cur][lg][wr + i * 16 + lr][0];
        #pragma unroll
        for (int j = 0; j < 4; j++) b[j] = *(const short8v*)&lB[cur][lg][wc + j * 16 + lr][0];
        #pragma unroll
        for (int i = 0; i < 4; i++)
            #pragma unroll
            for (int j = 0; j < 4; j++)
                acc[i][j] = MFMA16(a[i], b[j], acc[i][j]);
        __syncthreads();
        cur ^= 1;
    }

    const int rr = lg * 4, cc0 = lr;
    #pragma unroll
    for (int i = 0; i < 4; i++)
        #pragma unroll
        for (int j = 0; j < 4; j++) {
            int c = bn + wc + j * 16 + cc0;
            float bv = bias[c];
            #pragma unroll
            for (int r4 = 0; r4 < 4; r4++) {
                int r = bm + wr + i * 16 + rr + r4;
                float v = acc[i][j][r4] + bv;
                size_t oidx = (size_t)r * Nf + c;
                if (EPI == 1) v += bf2f(res[oidx]);
                if (EPI == 2) v = 0.5f * v * (1.f + erff(v * 0.70710678118654752f));
                if (EPI == 3) {
                    outf[oidx] = v + bf2f(res[oidx]);
                } else {
                    outb[oidx] = f2bf(v);
                }
            }
        }
}

// ---------------- MFMA attention: one block per (b,a), 4 waves, 8 heads ----------------
__global__ __launch_bounds__(256) void attn_mfma(
        const u16* __restrict__ qkv, const unsigned char* __restrict__ mask,
        u16* __restrict__ out) {
    __shared__ u16 sk[128][32];
    __shared__ u16 svt[32][136];
    __shared__ u16 sp[4][32][136];
    __shared__ unsigned char smask[128];
    const int ba = blockIdx.x;
    const size_t rowbase = (size_t)ba * Tc;
    const int tid  = threadIdx.x;
    const int lane = tid & 63;
    const int wave = tid >> 6;
    const int wq0  = wave * 32;
    const int lrow = lane & 15, lg = lane >> 4;
    if (tid < 128) smask[tid] = mask[rowbase + tid];

    const float scale  = 0.17677669529663687f;
    const float inv128 = 1.0f / 128.0f;
    const float4v zero4 = {0.f, 0.f, 0.f, 0.f};

    for (int h = 0; h < Hc; h++) {
        {
            const int r = tid >> 1, half = tid & 1;
            const u16* gbase = qkv + (rowbase + r) * 768 + h * 32 + half * 16;
            uint4 k0 = *(const uint4*)(gbase + 256);
            uint4 k1 = *(const uint4*)(gbase + 256 + 8);
            *(uint4*)&sk[r][half * 16]     = k0;
            *(uint4*)&sk[r][half * 16 + 8] = k1;
            uint4 v0 = *(const uint4*)(gbase + 512);
            uint4 v1 = *(const uint4*)(gbase + 512 + 8);
            u16 vt[16];
            *(uint4*)&vt[0] = v0; *(uint4*)&vt[8] = v1;
            #pragma unroll
            for (int e = 0; e < 16; e++) svt[half * 16 + e][r] = vt[e];
        }
        __syncthreads();

        short8v a0, a1;
        {
            const u16* qp0 = qkv + (rowbase + wq0 + lrow) * 768 + h * 32 + lg * 8;
            const u16* qp1 = qp0 + 16 * 768;
            a0 = *(const short8v*)qp0;
            a1 = *(const short8v*)qp1;
        }
        float4v s_acc[2][8];
        #pragma unroll
        for (int j = 0; j < 8; j++) {
            short8v bj = *(const short8v*)&sk[j * 16 + lrow][lg * 8];
            s_acc[0][j] = MFMA16(a0, bj, zero4);
            s_acc[1][j] = MFMA16(a1, bj, zero4);
        }

        #pragma unroll
        for (int i = 0; i < 2; i++) {
            #pragma unroll
            for (int r = 0; r < 4; r++) {
                float m = s_acc[i][0][r];
                #pragma unroll
                for (int j = 1; j < 8; j++) m = fmaxf(m, s_acc[i][j][r]);
                #pragma unroll
                for (int off = 1; off < 16; off <<= 1) m = fmaxf(m, __shfl_xor(m, off));
                float sum = 0.f;
                #pragma unroll
                for (int j = 0; j < 8; j++) {
                    float e = __expf((s_acc[i][j][r] - m) * scale);
                    sum += e;
                    s_acc[i][j][r] = e;
                }
                #pragma unroll
                for (int off = 1; off < 16; off <<= 1) sum += __shfl_xor(sum, off);
                const int qloc = i * 16 + lg * 4 + r;
                const bool mk = smask[wq0 + qloc] != 0;
                const float invs = 1.f / sum;
                #pragma unroll
                for (int j = 0; j < 8; j++) {
                    float pv = mk ? inv128 : s_acc[i][j][r] * invs;
                    sp[wave][qloc][j * 16 + lrow] = f2bf(pv);
                }
            }
        }

        float4v o_acc[2][2] = {};
        #pragma unroll
        for (int t = 0; t < 4; t++) {
            short8v pa0 = *(const short8v*)&sp[wave][lrow][t * 32 + lg * 8];
            short8v pa1 = *(const short8v*)&sp[wave][16 + lrow][t * 32 + lg * 8];
            short8v vb0 = *(const short8v*)&svt[lrow][t * 32 + lg * 8];
            short8v vb1 = *(const short8v*)&svt[16 + lrow][t * 32 + lg * 8];
            o_acc[0][0] = MFMA16(pa0, vb0, o_acc[0][0]);
            o_acc[0][1] = MFMA16(pa0, vb1, o_acc[0][1]);
            o_acc[1][0] = MFMA16(pa1, vb0, o_acc[1][0]);
            o_acc[1][1] = MFMA16(pa1, vb1, o_acc[1][1]);
        }

        #pragma unroll
        for (int i = 0; i < 2; i++)
            #pragma unroll
            for (int n = 0; n < 2; n++)
                #pragma unroll
                for (int r = 0; r < 4; r++) {
                    size_t row = rowbase + wq0 + i * 16 + lg * 4 + r;
                    int col = h * 32 + n * 16 + lrow;
                    out[row * 256 + col] = f2bf(o_acc[i][n][r]);
                }
        __syncthreads();
    }
}

extern "C" void kernel_launch(void* const* d_in, const int* in_sizes, int n_in,
                              void* d_out, int out_size, void* d_ws, size_t ws_size,
                              hipStream_t stream) {
    const float* x      = (const float*)d_in[0];
    const unsigned char* mask = (const unsigned char*)d_in[1];
    const float* ln1_w  = (const float*)d_in[2];
    const float* ln1_b  = (const float*)d_in[3];
    const float* qkv_w  = (const float*)d_in[4];
    const float* qkv_b  = (const float*)d_in[5];
    const float* proj_w = (const float*)d_in[6];
    const float* proj_b = (const float*)d_in[7];
    const float* ln2_w  = (const float*)d_in[8];
    const float* ln2_b  = (const float*)d_in[9];
    const float* fc1_w  = (const float*)d_in[10];
    const float* fc1_b  = (const float*)d_in[11];
    const float* fc2_w  = (const float*)d_in[12];
    const float* fc2_b  = (const float*)d_in[13];
    float* out = (float*)d_out;

    char* ws = (char*)d_ws;
    size_t off = 0;
    auto alloc = [&](size_t elems) -> u16* {
        u16* p = (u16*)(ws + off);
        off += ((elems * 2 + 255) / 256) * 256;
        return p;
    };
    u16* wqb  = alloc(768 * 256);
    u16* wpb  = alloc(256 * 256);
    u16* w1b  = alloc(1024 * 256);
    u16* w2b  = alloc(256 * 1024);
    u16* x1b  = alloc((size_t)NROW * Cc);
    u16* qkvb = alloc((size_t)NROW * 3 * Cc);
    u16* attb = alloc((size_t)NROW * Cc);
    u16* x2b  = alloc((size_t)NROW * Cc);
    u16* hb   = qkvb;   // fc1 output reuses qkv(3NC)+attn(NC) region = 4NC
    u16* x3b  = x1b;    // x3 reuses x1 region (x1 dead after proj)

    cast4_kernel<<<(786432 + 255) / 256, 256, 0, stream>>>(
        qkv_w, 196608, proj_w, 65536, fc1_w, 262144, fc2_w, 262144,
        wqb, wpb, w1b, w2b);
    ln_f32<<<NROW / 4, 256, 0, stream>>>(x, ln1_w, ln1_b, x1b);
    // qkv: 512 blocks x 512 thr, 12 chunks of 64 cols
    gemm_ares<12, 0><<<NROW / 128, 512, 0, stream>>>(
        x1b, wqb, qkv_b, qkvb, nullptr, 768);
    attn_mfma<<<Bc * Ac, 256, 0, stream>>>(qkvb, mask, attb);
    // proj + residual(x1)
    gemm_ares<4, 1><<<NROW / 128, 512, 0, stream>>>(
        attb, wpb, proj_b, x2b, x1b, 256);
    ln_bf16<<<NROW / 4, 256, 0, stream>>>(x2b, ln2_w, ln2_b, x3b);
    // fc1 + GELU
    gemm_ares<16, 2><<<NROW / 128, 512, 0, stream>>>(
        x3b, w1b, fc1_b, hb, nullptr, 1024);
    // fc2 + residual(x3) -> fp32 out: K=1024, deep loop
    gemm128<1024, 3><<<512 * 2, 256, 0, stream>>>(
        hb, w2b, fc2_b, nullptr, out, x3b, 256, 2);
}